// Round 3
// baseline (220.458 us; speedup 1.0000x reference)
//
#include <hip/hip_runtime.h>

// phi = exp2(-S2*d2), S2 = 1/(2*ls^2*ln2) = 8.014973
// e = 2*S2*(x.c) - S2*|c|^2 - S2*|x|^2  =  a1*x + a2*y + a3*z + a4*1 + 1*PX
// Computed via mfma_f32_16x16x32_bf16 with split-bf16 (hi + residual-lo)
// features, K slots (A-side x B-side):
//   [a1h*xh, a1h*xl, a1l*xh,  a2h*yh, a2h*yl, a2l*yh,
//    a3h*zh, a3h*zl, a3l*zh,  a4h*1, a4l*1,  1*PXh, 1*PXl, 0,0,0]
// Dropped lo*lo terms: |err(e)| <= ~3e-3 -> phi rel err <= 2e-3.
// SWAPPED operands (A=centers, B=points): D layout col=lane&15=point,
// row=(lane>>4)*4+reg=center  ->  exp2 + fp32 accumulation are lane-local,
// only a 4-group shfl_xor reduce at the very end.
#define S2 8.014973f
#define K2 16.029946f
#define ONEB ((unsigned short)0x3F80)  // bf16(1.0)

typedef float f32x4 __attribute__((ext_vector_type(4)));
typedef short bf16x8 __attribute__((ext_vector_type(8)));

__device__ __forceinline__ unsigned short bhi(float v) {  // RNE f32->bf16
    unsigned int b = __builtin_bit_cast(unsigned int, v);
    return (unsigned short)((b + 0x7FFFu + ((b >> 16) & 1u)) >> 16);
}
__device__ __forceinline__ float bf2f(unsigned short h) {
    unsigned int u = ((unsigned int)h) << 16;
    return __builtin_bit_cast(float, u);
}

// One block (1 wave) per 16-center tile T: writes
//  afrag[T*64+lane] = A-fragment uint4 (8 bf16): row=lane&15, k=8*(lane>>4)+e
//  bpack[(T*12 + g*3 + comp)*4 + r] = coeff[comp][16T+4g+r] (D-layout floats)
__global__ void rbf_prep(const float* __restrict__ centers,
                         const float* __restrict__ cu,
                         const float* __restrict__ cv,
                         const float* __restrict__ cw,
                         uint4* __restrict__ afrag,
                         float* __restrict__ bpack, int M) {
    const int T = blockIdx.x;
    const int lane = threadIdx.x;
    const int row = lane & 15, g = lane >> 4;
    const int c = T * 16 + row;
    float cx = 0.f, cy = 0.f, cz = 0.f;
    if (c < M) { cx = centers[3*c]; cy = centers[3*c+1]; cz = centers[3*c+2]; }
    const float a1 = K2 * cx, a2 = K2 * cy, a3 = K2 * cz;
    const float a4 = -S2 * (cx*cx + cy*cy + cz*cz);
    const unsigned short a1h = bhi(a1), a2h = bhi(a2), a3h = bhi(a3), a4h = bhi(a4);
    const unsigned short a1l = bhi(a1 - bf2f(a1h));
    const unsigned short a2l = bhi(a2 - bf2f(a2h));
    const unsigned short a3l = bhi(a3 - bf2f(a3h));
    const unsigned short a4l = bhi(a4 - bf2f(a4h));
    const unsigned short F[16] = {a1h, a1h, a1l, a2h, a2h, a2l, a3h, a3h,
                                  a3l, a4h, a4l, ONEB, ONEB, 0, 0, 0};
    uint4 u;  // prep is tiny; scratch from dynamic F index is fine here
    u.x = (unsigned int)F[8*g+0] | ((unsigned int)F[8*g+1] << 16);
    u.y = (unsigned int)F[8*g+2] | ((unsigned int)F[8*g+3] << 16);
    u.z = (unsigned int)F[8*g+4] | ((unsigned int)F[8*g+5] << 16);
    u.w = (unsigned int)F[8*g+6] | ((unsigned int)F[8*g+7] << 16);
    afrag[T * 64 + lane] = u;

    if (lane < 48) {
        const int g2 = lane / 12, idx = lane % 12;
        const int comp = idx >> 2, r = idx & 3;
        const int c2 = T * 16 + g2 * 4 + r;
        float v = 0.f;  // padded centers get coeff 0 -> contribute nothing
        if (c2 < M)
            v = (comp == 0) ? cu[c2] : ((comp == 1) ? cv[c2] : cw[c2]);
        bpack[(T * 12 + g2 * 3 + comp) * 4 + r] = v;
    }
}

// 1 wave per 16 points; loops over all center tiles. No LDS, no barriers,
// no atomics. grid = N/16 = 6250 blocks -> ~24 jobs/CU, tail ~2%.
__global__ __launch_bounds__(64) void rbf_main(
        const float* __restrict__ x,
        const uint4* __restrict__ afrag,
        const float4* __restrict__ bpack4,
        float* __restrict__ out, int N, int NT) {
    const int lane = threadIdx.x;
    const int col = lane & 15, g = lane >> 4;
    const int p = blockIdx.x * 16 + col;
    float xx = 0.f, xy = 0.f, xz = 0.f;
    if (p < N) { xx = x[3*p]; xy = x[3*p+1]; xz = x[3*p+2]; }
    const float px = -S2 * (xx*xx + xy*xy + xz*xz);

    // B-fragment: col=lane&15=point, k=8*(lane>>4)+e. Point features:
    // [xh,xl,xh, yh,yl,yh, zh,zl,zh, 1,1, PXh,PXl, 0,0,0]
    const unsigned short xh = bhi(xx), yh = bhi(xy), zh = bhi(xz);
    const unsigned short xl = bhi(xx - bf2f(xh));
    const unsigned short yl = bhi(xy - bf2f(yh));
    const unsigned short zl = bhi(xz - bf2f(zh));
    const unsigned short ph = bhi(px), pl = bhi(px - bf2f(ph));
    unsigned int b0 = 0, b1 = 0, b2 = 0, b3 = 0;
    if (g == 0) {            // k = 0..7
        b0 = (unsigned int)xh | ((unsigned int)xl << 16);
        b1 = (unsigned int)xh | ((unsigned int)yh << 16);
        b2 = (unsigned int)yl | ((unsigned int)yh << 16);
        b3 = (unsigned int)zh | ((unsigned int)zl << 16);
    } else if (g == 1) {     // k = 8..15
        b0 = (unsigned int)zh | ((unsigned int)ONEB << 16);
        b1 = (unsigned int)ONEB | ((unsigned int)ph << 16);
        b2 = (unsigned int)pl;  // (pl, 0)
        b3 = 0;
    }                         // g = 2,3: zero (k = 16..31 unused)
    uint4 bu_;
    bu_.x = b0; bu_.y = b1; bu_.z = b2; bu_.w = b3;
    const bf16x8 bfrag = __builtin_bit_cast(bf16x8, bu_);
    const f32x4 zero = {0.f, 0.f, 0.f, 0.f};

    float au = 0.f, av = 0.f, aw = 0.f;
    const uint4* __restrict__ ap = afrag + lane;        // coalesced stream
    const float4* __restrict__ bp = bpack4 + g * 3;     // broadcast per group

#pragma unroll 2
    for (int T = 0; T < NT; ++T) {
        const uint4 a = ap[T * 64];
        const float4 bu = bp[T * 12 + 0];
        const float4 bv = bp[T * 12 + 1];
        const float4 bw = bp[T * 12 + 2];
        const f32x4 E = __builtin_amdgcn_mfma_f32_16x16x32_bf16(
            __builtin_bit_cast(bf16x8, a), bfrag, zero, 0, 0, 0);
        const float p0 = __builtin_amdgcn_exp2f(E[0]);
        const float p1 = __builtin_amdgcn_exp2f(E[1]);
        const float p2 = __builtin_amdgcn_exp2f(E[2]);
        const float p3 = __builtin_amdgcn_exp2f(E[3]);
        au = fmaf(p0, bu.x, au); au = fmaf(p1, bu.y, au);
        au = fmaf(p2, bu.z, au); au = fmaf(p3, bu.w, au);
        av = fmaf(p0, bv.x, av); av = fmaf(p1, bv.y, av);
        av = fmaf(p2, bv.z, av); av = fmaf(p3, bv.w, av);
        aw = fmaf(p0, bw.x, aw); aw = fmaf(p1, bw.y, aw);
        aw = fmaf(p2, bw.z, aw); aw = fmaf(p3, bw.w, aw);
    }

    // Each lane group g covered centers {16T + 4g + r}; reduce over g.
    au += __shfl_xor(au, 16); au += __shfl_xor(au, 32);
    av += __shfl_xor(av, 16); av += __shfl_xor(av, 32);
    aw += __shfl_xor(aw, 16); aw += __shfl_xor(aw, 32);

    if (g == 0 && p < N) {
        const float r = sqrtf(xx*xx + xy*xy + xz*xz);
        const float s = 1.f - r;
        out[3*p+0] = fmaf(xx, s, au);
        out[3*p+1] = fmaf(xy, s, av);
        out[3*p+2] = fmaf(xz, s, aw);
    }
}

extern "C" void kernel_launch(void* const* d_in, const int* in_sizes, int n_in,
                              void* d_out, int out_size, void* d_ws,
                              size_t ws_size, hipStream_t stream) {
    const float* x = (const float*)d_in[0];
    const float* centers = (const float*)d_in[1];
    const float* cu = (const float*)d_in[2];
    const float* cv = (const float*)d_in[3];
    const float* cw = (const float*)d_in[4];
    float* out = (float*)d_out;
    const int N = in_sizes[0] / 3;
    const int M = in_sizes[1] / 3;
    const int NT = (M + 15) / 16;

    uint4* afrag = (uint4*)d_ws;                              // NT*1024 B
    float* bpack = (float*)((char*)d_ws + (size_t)NT * 1024); // NT*192 B

    hipLaunchKernelGGL(rbf_prep, dim3(NT), dim3(64), 0, stream,
                       centers, cu, cv, cw, afrag, bpack, M);
    hipLaunchKernelGGL(rbf_main, dim3((N + 15) / 16), dim3(64), 0, stream,
                       x, afrag, (const float4*)bpack, out, N, NT);
}

// Round 4
// 165.012 us; speedup vs baseline: 1.3360x; 1.3360x over previous
//
#include <hip/hip_runtime.h>

// phi = exp2(-S2*d2), S2 = 1/(2*ls^2*ln2) = 8.014973
// e = 2*S2*(x.c) - S2*|c|^2 - S2*|x|^2  =  a1*x + a2*y + a3*z + a4*1 + 1*PX
// Computed via mfma_f32_16x16x32_bf16 with split-bf16 (hi + residual-lo)
// features; dropped lo*lo terms -> |err(e)| ~ 1e-4 (products of two
// residuals), phi rel err negligible vs 0.0625 budget.
// SWAPPED operands (A=centers, B=points): D layout col=lane&15=point,
// row=(lane>>4)*4+reg=center -> exp2 + fp32 PV accumulation are lane-local.
// R4: PT=4 point tiles (64 points) per wave. Same 4 VMEM loads per
// center-tile iteration now feed 4 MFMAs + 16 exp2 + 48 fma -> 4x arithmetic
// intensity per load; R3 was latency-bound (VALUBusy 38.7%, 1 short body
// behind every L2-hit load chain).
#define S2 8.014973f
#define K2 16.029946f
#define ONEB ((unsigned short)0x3F80)  // bf16(1.0)
#define PT 4

typedef float f32x4 __attribute__((ext_vector_type(4)));
typedef short bf16x8 __attribute__((ext_vector_type(8)));

__device__ __forceinline__ unsigned short bhi(float v) {  // RNE f32->bf16
    unsigned int b = __builtin_bit_cast(unsigned int, v);
    return (unsigned short)((b + 0x7FFFu + ((b >> 16) & 1u)) >> 16);
}
__device__ __forceinline__ float bf2f(unsigned short h) {
    unsigned int u = ((unsigned int)h) << 16;
    return __builtin_bit_cast(float, u);
}

// One block (1 wave) per 16-center tile T: writes
//  afrag[T*64+lane] = A-fragment uint4 (8 bf16): row=lane&15, k=8*(lane>>4)+e
//  bpack[(T*12 + g*3 + comp)*4 + r] = coeff[comp][16T+4g+r] (D-layout floats)
__global__ void rbf_prep(const float* __restrict__ centers,
                         const float* __restrict__ cu,
                         const float* __restrict__ cv,
                         const float* __restrict__ cw,
                         uint4* __restrict__ afrag,
                         float* __restrict__ bpack, int M) {
    const int T = blockIdx.x;
    const int lane = threadIdx.x;
    const int row = lane & 15, g = lane >> 4;
    const int c = T * 16 + row;
    float cx = 0.f, cy = 0.f, cz = 0.f;
    if (c < M) { cx = centers[3*c]; cy = centers[3*c+1]; cz = centers[3*c+2]; }
    const float a1 = K2 * cx, a2 = K2 * cy, a3 = K2 * cz;
    const float a4 = -S2 * (cx*cx + cy*cy + cz*cz);
    const unsigned short a1h = bhi(a1), a2h = bhi(a2), a3h = bhi(a3), a4h = bhi(a4);
    const unsigned short a1l = bhi(a1 - bf2f(a1h));
    const unsigned short a2l = bhi(a2 - bf2f(a2h));
    const unsigned short a3l = bhi(a3 - bf2f(a3h));
    const unsigned short a4l = bhi(a4 - bf2f(a4h));
    const unsigned short F[16] = {a1h, a1h, a1l, a2h, a2h, a2l, a3h, a3h,
                                  a3l, a4h, a4l, ONEB, ONEB, 0, 0, 0};
    uint4 u;  // prep is tiny; scratch from dynamic F index is fine here
    u.x = (unsigned int)F[8*g+0] | ((unsigned int)F[8*g+1] << 16);
    u.y = (unsigned int)F[8*g+2] | ((unsigned int)F[8*g+3] << 16);
    u.z = (unsigned int)F[8*g+4] | ((unsigned int)F[8*g+5] << 16);
    u.w = (unsigned int)F[8*g+6] | ((unsigned int)F[8*g+7] << 16);
    afrag[T * 64 + lane] = u;

    if (lane < 48) {
        const int g2 = lane / 12, idx = lane % 12;
        const int comp = idx >> 2, r = idx & 3;
        const int c2 = T * 16 + g2 * 4 + r;
        float v = 0.f;  // padded centers get coeff 0 -> contribute nothing
        if (c2 < M)
            v = (comp == 0) ? cu[c2] : ((comp == 1) ? cv[c2] : cw[c2]);
        bpack[(T * 12 + g2 * 3 + comp) * 4 + r] = v;
    }
}

// 1 wave per 64 points (4 x 16-point MFMA tiles); loops over center tiles.
// grid = N/64 = 1563 blocks (~6.1/CU). No LDS, no barriers, no atomics.
__global__ __launch_bounds__(64) void rbf_main(
        const float* __restrict__ x,
        const uint4* __restrict__ afrag,
        const float4* __restrict__ bpack4,
        float* __restrict__ out, int N, int NT) {
    const int lane = threadIdx.x;
    const int col = lane & 15, g = lane >> 4;
    const int pb = blockIdx.x * (16 * PT);

    float xx[PT], xy[PT], xz[PT];
    bf16x8 bfrag[PT];
#pragma unroll
    for (int t = 0; t < PT; ++t) {
        const int p = pb + t * 16 + col;
        float a0 = 0.f, a1 = 0.f, a2 = 0.f;
        if (p < N) { a0 = x[3*p]; a1 = x[3*p+1]; a2 = x[3*p+2]; }
        xx[t] = a0; xy[t] = a1; xz[t] = a2;
        const float px = -S2 * (a0*a0 + a1*a1 + a2*a2);
        // B-fragment: col=lane&15=point, k=8*(lane>>4)+e. Point features:
        // [xh,xl,xh, yh,yl,yh, zh,zl,zh, 1,1, PXh,PXl, 0,0,0]
        const unsigned short xh = bhi(a0), yh = bhi(a1), zh = bhi(a2);
        const unsigned short xl = bhi(a0 - bf2f(xh));
        const unsigned short yl = bhi(a1 - bf2f(yh));
        const unsigned short zl = bhi(a2 - bf2f(zh));
        const unsigned short ph = bhi(px), pl = bhi(px - bf2f(ph));
        unsigned int b0 = 0, b1 = 0, b2 = 0, b3 = 0;
        if (g == 0) {            // k = 0..7
            b0 = (unsigned int)xh | ((unsigned int)xl << 16);
            b1 = (unsigned int)xh | ((unsigned int)yh << 16);
            b2 = (unsigned int)yl | ((unsigned int)yh << 16);
            b3 = (unsigned int)zh | ((unsigned int)zl << 16);
        } else if (g == 1) {     // k = 8..15
            b0 = (unsigned int)zh | ((unsigned int)ONEB << 16);
            b1 = (unsigned int)ONEB | ((unsigned int)ph << 16);
            b2 = (unsigned int)pl;  // (pl, 0)
            b3 = 0;
        }                         // g = 2,3: zero (k = 16..31 unused)
        uint4 bu_;
        bu_.x = b0; bu_.y = b1; bu_.z = b2; bu_.w = b3;
        bfrag[t] = __builtin_bit_cast(bf16x8, bu_);
    }

    const f32x4 zero = {0.f, 0.f, 0.f, 0.f};
    float au[PT], av[PT], aw[PT];
#pragma unroll
    for (int t = 0; t < PT; ++t) { au[t] = 0.f; av[t] = 0.f; aw[t] = 0.f; }

    const uint4* __restrict__ ap = afrag + lane;        // coalesced stream
    const float4* __restrict__ bp = bpack4 + g * 3;     // per-group broadcast

#pragma unroll 2
    for (int T = 0; T < NT; ++T) {
        const uint4 a = ap[T * 64];
        const float4 bu = bp[T * 12 + 0];
        const float4 bv = bp[T * 12 + 1];
        const float4 bw = bp[T * 12 + 2];
        const bf16x8 af = __builtin_bit_cast(bf16x8, a);
#pragma unroll
        for (int t = 0; t < PT; ++t) {
            const f32x4 E = __builtin_amdgcn_mfma_f32_16x16x32_bf16(
                af, bfrag[t], zero, 0, 0, 0);
            const float p0 = __builtin_amdgcn_exp2f(E[0]);
            const float p1 = __builtin_amdgcn_exp2f(E[1]);
            const float p2 = __builtin_amdgcn_exp2f(E[2]);
            const float p3 = __builtin_amdgcn_exp2f(E[3]);
            au[t] = fmaf(p0, bu.x, au[t]); au[t] = fmaf(p1, bu.y, au[t]);
            au[t] = fmaf(p2, bu.z, au[t]); au[t] = fmaf(p3, bu.w, au[t]);
            av[t] = fmaf(p0, bv.x, av[t]); av[t] = fmaf(p1, bv.y, av[t]);
            av[t] = fmaf(p2, bv.z, av[t]); av[t] = fmaf(p3, bv.w, av[t]);
            aw[t] = fmaf(p0, bw.x, aw[t]); aw[t] = fmaf(p1, bw.y, aw[t]);
            aw[t] = fmaf(p2, bw.z, aw[t]); aw[t] = fmaf(p3, bw.w, aw[t]);
        }
    }

    // Each lane group g covered centers {16T + 4g + r}; reduce over g.
#pragma unroll
    for (int t = 0; t < PT; ++t) {
        au[t] += __shfl_xor(au[t], 16); au[t] += __shfl_xor(au[t], 32);
        av[t] += __shfl_xor(av[t], 16); av[t] += __shfl_xor(av[t], 32);
        aw[t] += __shfl_xor(aw[t], 16); aw[t] += __shfl_xor(aw[t], 32);
    }

    if (g == 0) {
#pragma unroll
        for (int t = 0; t < PT; ++t) {
            const int p = pb + t * 16 + col;
            if (p < N) {
                const float r = sqrtf(xx[t]*xx[t] + xy[t]*xy[t] + xz[t]*xz[t]);
                const float s = 1.f - r;
                out[3*p+0] = fmaf(xx[t], s, au[t]);
                out[3*p+1] = fmaf(xy[t], s, av[t]);
                out[3*p+2] = fmaf(xz[t], s, aw[t]);
            }
        }
    }
}

extern "C" void kernel_launch(void* const* d_in, const int* in_sizes, int n_in,
                              void* d_out, int out_size, void* d_ws,
                              size_t ws_size, hipStream_t stream) {
    const float* x = (const float*)d_in[0];
    const float* centers = (const float*)d_in[1];
    const float* cu = (const float*)d_in[2];
    const float* cv = (const float*)d_in[3];
    const float* cw = (const float*)d_in[4];
    float* out = (float*)d_out;
    const int N = in_sizes[0] / 3;
    const int M = in_sizes[1] / 3;
    const int NT = (M + 15) / 16;

    uint4* afrag = (uint4*)d_ws;                              // NT*1024 B
    float* bpack = (float*)((char*)d_ws + (size_t)NT * 1024); // NT*192 B

    hipLaunchKernelGGL(rbf_prep, dim3(NT), dim3(64), 0, stream,
                       centers, cu, cv, cw, afrag, bpack, M);
    hipLaunchKernelGGL(rbf_main, dim3((N + 16 * PT - 1) / (16 * PT)), dim3(64),
                       0, stream, x, afrag, (const float4*)bpack, out, N, NT);
}

// Round 5
// 133.145 us; speedup vs baseline: 1.6558x; 1.2393x over previous
//
#include <hip/hip_runtime.h>

// phi = exp2(-S2*d2), S2 = 1/(2*ls^2*ln2) = 8.014973
// e = 2*S2*(x.c) - S2*|c|^2 - S2*|x|^2  =  a1*x + a2*y + a3*z + a4*1 + 1*PX
// via mfma_f32_16x16x32_bf16, split-bf16 (hi + residual-lo) features.
// SWAPPED operands (A=centers, B=points): D layout col=lane&15=point,
// row=(lane>>4)*4+reg=center -> exp2 + fp32 PV accumulation lane-local.
// R5: 4-wave blocks. Block owns 64 points (PT=4 MFMA tiles); each wave owns
// 1/4 of the center tiles; 3KB LDS cross-wave reduce. Waves 1563->6252
// (R4 had 6 waves/CU = 16.7% occupancy -> latency-bound, VALUBusy 42%).
// Pipe model: exp2 ~16cy/wave-instr -> 34us trans floor; PV-fma 13us VALU;
// MFMA 8.5us -- separate pipes, overlap across 24 waves/CU.
#define S2 8.014973f
#define K2 16.029946f
#define ONEB ((unsigned short)0x3F80)  // bf16(1.0)
#define PT 4
#define BW 4  // waves per block (center-split ways)

typedef float f32x4 __attribute__((ext_vector_type(4)));
typedef short bf16x8 __attribute__((ext_vector_type(8)));

__device__ __forceinline__ unsigned short bhi(float v) {  // RNE f32->bf16
    unsigned int b = __builtin_bit_cast(unsigned int, v);
    return (unsigned short)((b + 0x7FFFu + ((b >> 16) & 1u)) >> 16);
}
__device__ __forceinline__ float bf2f(unsigned short h) {
    unsigned int u = ((unsigned int)h) << 16;
    return __builtin_bit_cast(float, u);
}

// One block (1 wave) per 16-center tile T: writes
//  afrag[T*64+lane] = A-fragment uint4 (8 bf16): row=lane&15, k=8*(lane>>4)+e
//  bpack[(T*12 + g*3 + comp)*4 + r] = coeff[comp][16T+4g+r] (D-layout floats)
__global__ void rbf_prep(const float* __restrict__ centers,
                         const float* __restrict__ cu,
                         const float* __restrict__ cv,
                         const float* __restrict__ cw,
                         uint4* __restrict__ afrag,
                         float* __restrict__ bpack, int M) {
    const int T = blockIdx.x;
    const int lane = threadIdx.x;
    const int row = lane & 15, g = lane >> 4;
    const int c = T * 16 + row;
    float cx = 0.f, cy = 0.f, cz = 0.f;
    if (c < M) { cx = centers[3*c]; cy = centers[3*c+1]; cz = centers[3*c+2]; }
    const float a1 = K2 * cx, a2 = K2 * cy, a3 = K2 * cz;
    const float a4 = -S2 * (cx*cx + cy*cy + cz*cz);
    const unsigned short a1h = bhi(a1), a2h = bhi(a2), a3h = bhi(a3), a4h = bhi(a4);
    const unsigned short a1l = bhi(a1 - bf2f(a1h));
    const unsigned short a2l = bhi(a2 - bf2f(a2h));
    const unsigned short a3l = bhi(a3 - bf2f(a3h));
    const unsigned short a4l = bhi(a4 - bf2f(a4h));
    const unsigned short F[16] = {a1h, a1h, a1l, a2h, a2h, a2l, a3h, a3h,
                                  a3l, a4h, a4l, ONEB, ONEB, 0, 0, 0};
    uint4 u;  // prep is tiny; scratch from dynamic F index is fine here
    u.x = (unsigned int)F[8*g+0] | ((unsigned int)F[8*g+1] << 16);
    u.y = (unsigned int)F[8*g+2] | ((unsigned int)F[8*g+3] << 16);
    u.z = (unsigned int)F[8*g+4] | ((unsigned int)F[8*g+5] << 16);
    u.w = (unsigned int)F[8*g+6] | ((unsigned int)F[8*g+7] << 16);
    afrag[T * 64 + lane] = u;

    if (lane < 48) {
        const int g2 = lane / 12, idx = lane % 12;
        const int comp = idx >> 2, r = idx & 3;
        const int c2 = T * 16 + g2 * 4 + r;
        float v = 0.f;  // padded centers get coeff 0 -> contribute nothing
        if (c2 < M)
            v = (comp == 0) ? cu[c2] : ((comp == 1) ? cv[c2] : cw[c2]);
        bpack[(T * 12 + g2 * 3 + comp) * 4 + r] = v;
    }
}

// Block = 256 thr = 4 waves; block owns 64 points (4 x 16-pt MFMA tiles).
// Wave w handles center tiles [w*per, (w+1)*per). LDS reduce across waves.
// grid = N/64 = 1563 blocks -> 6252 waves (~24/CU).
__global__ __launch_bounds__(256) void rbf_main(
        const float* __restrict__ x,
        const uint4* __restrict__ afrag,
        const float4* __restrict__ bpack4,
        float* __restrict__ out, int N, int NT) {
    __shared__ float acc[BW][64][3];

    const int tid = threadIdx.x;
    const int lane = tid & 63;
    const int w = __builtin_amdgcn_readfirstlane(tid >> 6);  // wave id
    const int col = lane & 15, g = lane >> 4;
    const int pb = blockIdx.x * (16 * PT);

    float xx[PT], xy[PT], xz[PT];
    bf16x8 bfrag[PT];
#pragma unroll
    for (int t = 0; t < PT; ++t) {
        const int p = pb + t * 16 + col;
        float a0 = 0.f, a1 = 0.f, a2 = 0.f;
        if (p < N) { a0 = x[3*p]; a1 = x[3*p+1]; a2 = x[3*p+2]; }
        xx[t] = a0; xy[t] = a1; xz[t] = a2;
        const float px = -S2 * (a0*a0 + a1*a1 + a2*a2);
        // B-fragment: col=lane&15=point, k=8*(lane>>4)+e. Point features:
        // [xh,xl,xh, yh,yl,yh, zh,zl,zh, 1,1, PXh,PXl, 0,0,0]
        const unsigned short xh = bhi(a0), yh = bhi(a1), zh = bhi(a2);
        const unsigned short xl = bhi(a0 - bf2f(xh));
        const unsigned short yl = bhi(a1 - bf2f(yh));
        const unsigned short zl = bhi(a2 - bf2f(zh));
        const unsigned short ph = bhi(px), pl = bhi(px - bf2f(ph));
        unsigned int b0 = 0, b1 = 0, b2 = 0, b3 = 0;
        if (g == 0) {            // k = 0..7
            b0 = (unsigned int)xh | ((unsigned int)xl << 16);
            b1 = (unsigned int)xh | ((unsigned int)yh << 16);
            b2 = (unsigned int)yl | ((unsigned int)yh << 16);
            b3 = (unsigned int)zh | ((unsigned int)zl << 16);
        } else if (g == 1) {     // k = 8..15
            b0 = (unsigned int)zh | ((unsigned int)ONEB << 16);
            b1 = (unsigned int)ONEB | ((unsigned int)ph << 16);
            b2 = (unsigned int)pl;  // (pl, 0)
            b3 = 0;
        }                         // g = 2,3: zero (k = 16..31 unused)
        uint4 bu_;
        bu_.x = b0; bu_.y = b1; bu_.z = b2; bu_.w = b3;
        bfrag[t] = __builtin_bit_cast(bf16x8, bu_);
    }

    const f32x4 zero = {0.f, 0.f, 0.f, 0.f};
    float au[PT], av[PT], aw[PT];
#pragma unroll
    for (int t = 0; t < PT; ++t) { au[t] = 0.f; av[t] = 0.f; aw[t] = 0.f; }

    const uint4* __restrict__ ap = afrag + lane;        // coalesced stream
    const float4* __restrict__ bp = bpack4 + g * 3;     // per-group broadcast

    // wave w owns center tiles [jb, je)
    const int per = (NT + BW - 1) / BW;
    const int jb = w * per;
    const int je = min(jb + per, NT);

#pragma unroll 2
    for (int T = jb; T < je; ++T) {
        const uint4 a = ap[T * 64];
        const float4 bu = bp[T * 12 + 0];
        const float4 bv = bp[T * 12 + 1];
        const float4 bw = bp[T * 12 + 2];
        const bf16x8 af = __builtin_bit_cast(bf16x8, a);
#pragma unroll
        for (int t = 0; t < PT; ++t) {
            const f32x4 E = __builtin_amdgcn_mfma_f32_16x16x32_bf16(
                af, bfrag[t], zero, 0, 0, 0);
            const float p0 = __builtin_amdgcn_exp2f(E[0]);
            const float p1 = __builtin_amdgcn_exp2f(E[1]);
            const float p2 = __builtin_amdgcn_exp2f(E[2]);
            const float p3 = __builtin_amdgcn_exp2f(E[3]);
            au[t] = fmaf(p0, bu.x, au[t]); au[t] = fmaf(p1, bu.y, au[t]);
            au[t] = fmaf(p2, bu.z, au[t]); au[t] = fmaf(p3, bu.w, au[t]);
            av[t] = fmaf(p0, bv.x, av[t]); av[t] = fmaf(p1, bv.y, av[t]);
            av[t] = fmaf(p2, bv.z, av[t]); av[t] = fmaf(p3, bv.w, av[t]);
            aw[t] = fmaf(p0, bw.x, aw[t]); aw[t] = fmaf(p1, bw.y, aw[t]);
            aw[t] = fmaf(p2, bw.z, aw[t]); aw[t] = fmaf(p3, bw.w, aw[t]);
        }
    }

    // Reduce over the 4 lane groups g (centers {16T + 4g + r}).
#pragma unroll
    for (int t = 0; t < PT; ++t) {
        au[t] += __shfl_xor(au[t], 16); au[t] += __shfl_xor(au[t], 32);
        av[t] += __shfl_xor(av[t], 16); av[t] += __shfl_xor(av[t], 32);
        aw[t] += __shfl_xor(aw[t], 16); aw[t] += __shfl_xor(aw[t], 32);
    }

    // Base field once per point: wave 0 only.
    if (w == 0 && g == 0) {
#pragma unroll
        for (int t = 0; t < PT; ++t) {
            const float r = sqrtf(xx[t]*xx[t] + xy[t]*xy[t] + xz[t]*xz[t]);
            const float s = 1.f - r;
            au[t] = fmaf(xx[t], s, au[t]);
            av[t] = fmaf(xy[t], s, av[t]);
            aw[t] = fmaf(xz[t], s, aw[t]);
        }
    }

    if (g == 0) {
#pragma unroll
        for (int t = 0; t < PT; ++t) {
            acc[w][t * 16 + col][0] = au[t];
            acc[w][t * 16 + col][1] = av[t];
            acc[w][t * 16 + col][2] = aw[t];
        }
    }
    __syncthreads();

    // 192 outputs per block, stride-1 across tid -> coalesced store.
    if (tid < 192) {
        const int gi = pb * 3 + tid;
        if (gi < 3 * N) {
            const int pl = tid / 3, c = tid % 3;
            float s = acc[0][pl][c] + acc[1][pl][c] +
                      acc[2][pl][c] + acc[3][pl][c];
            out[gi] = s;
        }
    }
}

extern "C" void kernel_launch(void* const* d_in, const int* in_sizes, int n_in,
                              void* d_out, int out_size, void* d_ws,
                              size_t ws_size, hipStream_t stream) {
    const float* x = (const float*)d_in[0];
    const float* centers = (const float*)d_in[1];
    const float* cu = (const float*)d_in[2];
    const float* cv = (const float*)d_in[3];
    const float* cw = (const float*)d_in[4];
    float* out = (float*)d_out;
    const int N = in_sizes[0] / 3;
    const int M = in_sizes[1] / 3;
    const int NT = (M + 15) / 16;

    uint4* afrag = (uint4*)d_ws;                              // NT*1024 B
    float* bpack = (float*)((char*)d_ws + (size_t)NT * 1024); // NT*192 B

    hipLaunchKernelGGL(rbf_prep, dim3(NT), dim3(64), 0, stream,
                       centers, cu, cv, cw, afrag, bpack, M);
    hipLaunchKernelGGL(rbf_main, dim3((N + 16 * PT - 1) / (16 * PT)),
                       dim3(256), 0, stream,
                       x, afrag, (const float4*)bpack, out, N, NT);
}